// Round 2
// baseline (437.913 us; speedup 1.0000x reference)
//
#include <hip/hip_runtime.h>

#define NN 207
#define NP 208
#define ALPHA 0.05f
#define BETA  0.95f

#define YS_STR 209
#define YS_HALF (32 * YS_STR)      // 6688
#define SBUF_FL (2 * YS_HALF)      // 13376 floats = 53504 B -> 3 blocks/CU (160.5KB <= 160KiB... 160512 <= 163840 OK)

// ws layout (floats): An @ 0 (207*207), A2 @ 43008, Pt @ 86016 (207*208)

__global__ __launch_bounds__(256) void k_norm(const float* __restrict__ adj,
                                              float* __restrict__ An) {
    int v = blockIdx.x;
    int t = threadIdx.x;
    __shared__ float red[4];
    __shared__ float sinv;
    float s = 0.f;
    if (t < NN) s = adj[v * NN + t];
    s += __shfl_down(s, 32);
    s += __shfl_down(s, 16);
    s += __shfl_down(s, 8);
    s += __shfl_down(s, 4);
    s += __shfl_down(s, 2);
    s += __shfl_down(s, 1);
    if ((t & 63) == 0) red[t >> 6] = s;
    __syncthreads();
    if (t == 0) sinv = 1.0f / (red[0] + red[1] + red[2] + red[3] + 1.0f);
    __syncthreads();
    float inv = sinv;
    if (t < NN) An[v * NN + t] = (adj[v * NN + t] + (t == v ? 1.f : 0.f)) * inv;
}

__global__ __launch_bounds__(256) void k_a2(const float* __restrict__ An,
                                            float* __restrict__ A2) {
    int v = blockIdx.x;
    int w = threadIdx.x;
    if (w < NN) {
        float s = 0.f;
        for (int u = 0; u < NN; ++u) s = fmaf(An[v * NN + u], An[u * NN + w], s);
        A2[v * NN + w] = s;
    }
}

__global__ __launch_bounds__(256) void k_p(const float* __restrict__ An,
                                           const float* __restrict__ A2,
                                           float* __restrict__ Pt) {
    int v = blockIdx.x;
    int w = threadIdx.x;
    if (w < NN) {
        float s = 0.f;
        for (int u = 0; u < NN; ++u) s = fmaf(A2[v * NN + u], An[u * NN + w], s);
        float p = (v == w ? ALPHA : 0.f)
                + (ALPHA * BETA) * An[v * NN + w]
                + (ALPHA * BETA * BETA) * A2[v * NN + w]
                + (BETA * BETA * BETA) * s;
        Pt[w * NP + v] = p;                 // transposed: [w][v], stride 208
        if (blockIdx.x == 0) Pt[w * NP + NN] = 0.f;   // zero pad column v=207
    }
}

// Fused: y[c,v,l] = sum_w Pt[w][v] * x[c,w,l]; out[o,v,l] = b[o] + sum_c W[o,c] y[c,v,l]
// Block = (n, l-chunk of 2), XCD-swizzled so the 6 sibling blocks of one n share an XCD L2.
__global__ __launch_bounds__(256) void k_main(const float* __restrict__ x,
                                              const float* __restrict__ Pt,
                                              const float* __restrict__ Wm,
                                              const float* __restrict__ bias,
                                              float* __restrict__ out) {
    __shared__ float sbuf[SBUF_FL];
    // phase 1 (xs): [w][l][c ^ (w&31)], max idx 13247 < 13376
    // phase 2 (ys): [lw][c][v], stride YS_STR=209

    const int b   = blockIdx.x;
    const int xcd = b & 7;
    const int q   = b >> 3;
    const int lc  = q % 6;
    const int ng  = q / 6;
    const int n   = ng * 8 + xcd;          // all 6 lc-siblings of n share b%8 -> same XCD
    const int l0  = lc * 2;
    const int t   = threadIdx.x;

    // ---- stage x[n, :, :, l0:l0+2] -> xs
    const float2* x2 = reinterpret_cast<const float2*>(x);
    #pragma unroll 4
    for (int cc = 0; cc < 32; ++cc) {
        if (t < NN) {
            const int w = t;
            float2 val = x2[(((size_t)(n * 32 + cc)) * NN + w) * 6 + (l0 >> 1)];
            const int cp = cc ^ (w & 31);
            sbuf[(w * 2 + 0) * 32 + cp] = val.x;
            sbuf[(w * 2 + 1) * 32 + cp] = val.y;
        }
    }
    __syncthreads();

    // ---- node mix: lane (c,lw), wave owns v in [vb, vb+52)
    const int c  = t & 31;
    const int lw = (t >> 5) & 1;
    const int wave = __builtin_amdgcn_readfirstlane(t >> 6);
    const int vb = wave * 52;

    float acc[52];
    #pragma unroll
    for (int j = 0; j < 52; ++j) acc[j] = 0.f;

    for (int w = 0; w < NN; ++w) {
        const float xv = sbuf[(w * 2 + lw) * 32 + (c ^ (w & 31))];
        const float* __restrict__ prow = Pt + w * NP + vb;   // wave-uniform -> s_load
        #pragma unroll
        for (int j = 0; j < 52; ++j) acc[j] = fmaf(prow[j], xv, acc[j]);
    }
    __syncthreads();   // xs consumed; reuse buffer as ys

    // ---- scatter y: ys[lw][c][v]  (17c+v mod 32 -> exactly 2 lanes/bank, free)
    #pragma unroll
    for (int j = 0; j < 52; ++j) {
        sbuf[lw * YS_HALF + c * YS_STR + (vb + j)] = acc[j];
    }
    __syncthreads();

    // ---- channel mix + bias + float2 store; thread = v (207 active)
    if (t < NN) {
        const int v = t;
        float y0[32], y1[32];
        #pragma unroll
        for (int cc = 0; cc < 32; ++cc) {
            y0[cc] = sbuf[cc * YS_STR + v];
            y1[cc] = sbuf[YS_HALF + cc * YS_STR + v];
        }
        float* op = out + ((size_t)(n * 32)) * (NN * 12) + v * 12 + l0;
        for (int o = 0; o < 32; ++o) {
            const float* wr = Wm + o * 32;   // wave-uniform -> s_load, shared by both l
            float a0 = bias[o];
            float a1 = a0;
            #pragma unroll
            for (int cc = 0; cc < 32; ++cc) {
                a0 = fmaf(wr[cc], y0[cc], a0);
                a1 = fmaf(wr[cc], y1[cc], a1);
            }
            *reinterpret_cast<float2*>(op + (size_t)o * (NN * 12)) = make_float2(a0, a1);
        }
    }
}

extern "C" void kernel_launch(void* const* d_in, const int* in_sizes, int n_in,
                              void* d_out, int out_size, void* d_ws, size_t ws_size,
                              hipStream_t stream) {
    const float* x   = (const float*)d_in[0];
    const float* adj = (const float*)d_in[1];
    const float* W   = (const float*)d_in[2];
    const float* b   = (const float*)d_in[3];
    float* out = (float*)d_out;
    float* ws  = (float*)d_ws;

    float* An = ws;
    float* A2 = ws + 43008;
    float* Pt = ws + 86016;

    k_norm<<<NN, 256, 0, stream>>>(adj, An);
    k_a2  <<<NN, 256, 0, stream>>>(An, A2);
    k_p   <<<NN, 256, 0, stream>>>(An, A2, Pt);
    k_main<<<256 * 6, 256, 0, stream>>>(x, Pt, W, b, out);
}

// Round 3
// 261.397 us; speedup vs baseline: 1.6753x; 1.6753x over previous
//
#include <hip/hip_runtime.h>

#define NN 207
#define ALPHA 0.05f
#define BETA  0.95f

typedef __attribute__((ext_vector_type(8))) short bf16x8;
typedef __attribute__((ext_vector_type(4))) float f32x4;

__device__ inline unsigned short f2bf(float f) {
    union { float f; unsigned int u; } v; v.f = f;
    unsigned int u = v.u;
    unsigned int r = (u + 0x7FFFu + ((u >> 16) & 1u)) >> 16;   // RNE
    return (unsigned short)r;
}

// ---- adjacency normalize + M1 = alpha*I + beta*An
__global__ __launch_bounds__(256) void k_norm(const float* __restrict__ adj,
                                              float* __restrict__ An,
                                              float* __restrict__ M1) {
    int v = blockIdx.x;
    int t = threadIdx.x;
    __shared__ float red[4];
    __shared__ float sinv;
    float s = 0.f;
    if (t < NN) s = adj[v * NN + t];
    s += __shfl_down(s, 32); s += __shfl_down(s, 16); s += __shfl_down(s, 8);
    s += __shfl_down(s, 4);  s += __shfl_down(s, 2);  s += __shfl_down(s, 1);
    if ((t & 63) == 0) red[t >> 6] = s;
    __syncthreads();
    if (t == 0) sinv = 1.0f / (red[0] + red[1] + red[2] + red[3] + 1.0f);
    __syncthreads();
    if (t < NN) {
        float val = (adj[v * NN + t] + (t == v ? 1.f : 0.f)) * sinv;
        An[v * NN + t] = val;
        M1[v * NN + t] = (t == v ? ALPHA : 0.f) + BETA * val;
    }
}

// ---- C = alpha*I + beta*(A @ X), 207x207, tiled 64x64, 16 blocks x 256 thr
__global__ __launch_bounds__(256) void k_step(const float* __restrict__ A,
                                              const float* __restrict__ X,
                                              float* __restrict__ C) {
    __shared__ float As[32][68];   // [k][i] transposed
    __shared__ float Xs[32][68];   // [k][j]
    const int t = threadIdx.x;
    const int bi = blockIdx.x;
    const int i0 = (bi >> 2) * 64, j0 = (bi & 3) * 64;
    const int ty = t >> 4, tx = t & 15;
    float acc[4][4] = {{0.f}};
    for (int kt = 0; kt < 7; ++kt) {
        __syncthreads();
        {
            int r = t >> 2, q = t & 3;
            int gi = i0 + r;
            #pragma unroll
            for (int h = 0; h < 2; ++h) {
                #pragma unroll
                for (int e = 0; e < 4; ++e) {
                    int u = kt * 32 + q * 8 + h * 4 + e;
                    float v = 0.f;
                    if (gi < NN && u < NN) v = A[gi * NN + u];
                    As[q * 8 + h * 4 + e][r] = v;
                }
            }
            int kk = t >> 3, p = t & 7;
            int gu = kt * 32 + kk;
            #pragma unroll
            for (int h = 0; h < 2; ++h) {
                #pragma unroll
                for (int e = 0; e < 4; ++e) {
                    int gj = j0 + p * 8 + h * 4 + e;
                    float v = 0.f;
                    if (gu < NN && gj < NN) v = X[gu * NN + gj];
                    Xs[kk][p * 8 + h * 4 + e] = v;
                }
            }
        }
        __syncthreads();
        #pragma unroll 8
        for (int kk = 0; kk < 32; ++kk) {
            float4 a = *(const float4*)&As[kk][ty * 4];
            float4 b = *(const float4*)&Xs[kk][tx * 4];
            const float* ap = &a.x; const float* bp = &b.x;
            #pragma unroll
            for (int ii = 0; ii < 4; ++ii)
                #pragma unroll
                for (int jj = 0; jj < 4; ++jj)
                    acc[ii][jj] = fmaf(ap[ii], bp[jj], acc[ii][jj]);
        }
    }
    #pragma unroll
    for (int ii = 0; ii < 4; ++ii) {
        int gi = i0 + ty * 4 + ii;
        if (gi < NN) {
            #pragma unroll
            for (int jj = 0; jj < 4; ++jj) {
                int gj = j0 + tx * 4 + jj;
                if (gj < NN)
                    C[gi * NN + gj] = (gi == gj ? ALPHA : 0.f) + BETA * acc[ii][jj];
            }
        }
    }
}

// ---- pack P (row-major [v][w]) into B-fragment order:
// Pbf[nt(13)][ks(7)][lane(64)][8 bf16]; lane = (v%16) + 16*kblk, k = ks*32+kblk*8+j
__global__ __launch_bounds__(64) void k_pack(const float* __restrict__ P,
                                             uint4* __restrict__ Pbf) {
    int g = blockIdx.x;           // 0..90
    int nt = g / 7, ks = g % 7;
    int lane = threadIdx.x;
    int v = nt * 16 + (lane & 15);
    int wb = ks * 32 + (lane >> 4) * 8;
    unsigned int d[4];
    #pragma unroll
    for (int p = 0; p < 4; ++p) {
        float lo = 0.f, hi = 0.f;
        int w = wb + 2 * p;
        if (v < NN) {
            if (w < NN)     lo = P[v * NN + w];
            if (w + 1 < NN) hi = P[v * NN + w + 1];
        }
        d[p] = (unsigned int)f2bf(lo) | ((unsigned int)f2bf(hi) << 16);
    }
    uint4 o; o.x = d[0]; o.y = d[1]; o.z = d[2]; o.w = d[3];
    Pbf[g * 64 + lane] = o;
}

// ---- main: per n, H[m=(c*12+l)][v] = sum_w x_bf16 * P_bf16 via MFMA, then fp32 channel mix
__global__ __launch_bounds__(512) void k_main(const float* __restrict__ x,
                                              const uint4* __restrict__ Pbf,
                                              const float* __restrict__ Wm,
                                              const float* __restrict__ bias,
                                              float* __restrict__ out) {
    __shared__ __align__(16) char lds[52224];     // afrag 24*1024 B | ys 384*34*4 B
    unsigned int* afrag = (unsigned int*)lds;
    float* ys = (float*)lds;

    const int n = blockIdx.x;
    const int t = threadIdx.x;
    const int lane = t & 63;
    const int wave = __builtin_amdgcn_readfirstlane(t >> 6);

    f32x4 acc[3][13];
    #pragma unroll
    for (int a = 0; a < 3; ++a)
        #pragma unroll
        for (int bI = 0; bI < 13; ++bI) acc[a][bI] = (f32x4)0.f;

    const float4* x4 = (const float4*)x;

    for (int ks = 0; ks < 7; ++ks) {
        __syncthreads();
        // stage A chunk: x[n][c][ks*32 + wc][l] -> bf16 fragments
        #pragma unroll
        for (int i = 0; i < 3; ++i) {
            int q = t + 512 * i;                  // 1536 tasks: (c, wpair, lseg)
            int c = q / 48, r = q % 48;
            int wp = r / 3, lseg = r % 3;
            int w0 = ks * 32 + 2 * wp;
            float4 va = make_float4(0.f, 0.f, 0.f, 0.f), vb = va;
            size_t base = (size_t)(n * 32 + c) * NN;
            if (w0 < NN)     va = x4[(base + w0) * 3 + lseg];
            if (w0 + 1 < NN) vb = x4[(base + w0 + 1) * 3 + lseg];
            int kblk = wp >> 2, dw = wp & 3;
            const float* vap = &va.x; const float* vbp = &vb.x;
            #pragma unroll
            for (int e = 0; e < 4; ++e) {
                int m = c * 12 + lseg * 4 + e;
                unsigned int pk = (unsigned int)f2bf(vap[e])
                                | ((unsigned int)f2bf(vbp[e]) << 16);
                afrag[(m >> 4) * 256 + ((m & 15) + 16 * kblk) * 4 + dw] = pk;
            }
        }
        __syncthreads();
        // compute: wave owns Mtiles [3*wave, 3*wave+3)
        bf16x8 af[3];
        #pragma unroll
        for (int mt3 = 0; mt3 < 3; ++mt3)
            af[mt3] = ((const bf16x8*)lds)[(wave * 3 + mt3) * 64 + lane];
        #pragma unroll
        for (int nt = 0; nt < 13; ++nt) {
            uint4 braw = Pbf[(nt * 7 + ks) * 64 + lane];
            bf16x8 bf = __builtin_bit_cast(bf16x8, braw);
            #pragma unroll
            for (int mt3 = 0; mt3 < 3; ++mt3)
                acc[mt3][nt] = __builtin_amdgcn_mfma_f32_16x16x32_bf16(
                                   af[mt3], bf, acc[mt3][nt], 0, 0, 0);
        }
    }

    // epilogue: 2 N-tiles per pass through LDS, fp32 channel mix
    #pragma unroll
    for (int np = 0; np < 7; ++np) {
        __syncthreads();
        #pragma unroll
        for (int tl = 0; tl < 2; ++tl) {
            int nt = np * 2 + tl;
            if (nt < 13) {
                #pragma unroll
                for (int mt3 = 0; mt3 < 3; ++mt3) {
                    int mrow = (wave * 3 + mt3) * 16 + (lane >> 4) * 4;
                    #pragma unroll
                    for (int r = 0; r < 4; ++r)
                        ys[(mrow + r) * 34 + tl * 16 + (lane & 15)] = acc[mt3][nt][r];
                }
            }
        }
        __syncthreads();
        if (t < 384) {
            int tl = t / 192, rr = t % 192;
            int vv = rr / 12, l = rr % 12;
            int v = (np * 2 + tl) * 16 + vv;
            if (v < NN) {
                float y[32];
                #pragma unroll
                for (int c = 0; c < 32; ++c)
                    y[c] = ys[(c * 12 + l) * 34 + tl * 16 + vv];
                size_t ob = (size_t)n * 32 * (NN * 12) + (size_t)v * 12 + l;
                for (int o = 0; o < 32; ++o) {
                    float a = bias[o];
                    #pragma unroll
                    for (int c = 0; c < 32; ++c)
                        a = fmaf(Wm[o * 32 + c], y[c], a);
                    out[ob + (size_t)o * (NN * 12)] = a;
                }
            }
        }
    }
}

extern "C" void kernel_launch(void* const* d_in, const int* in_sizes, int n_in,
                              void* d_out, int out_size, void* d_ws, size_t ws_size,
                              hipStream_t stream) {
    const float* x   = (const float*)d_in[0];
    const float* adj = (const float*)d_in[1];
    const float* W   = (const float*)d_in[2];
    const float* b   = (const float*)d_in[3];
    float* out = (float*)d_out;
    float* ws  = (float*)d_ws;

    float* An  = ws;            // dead after 2nd k_step
    float* M1P = ws + 43008;    // M1, then P
    float* M2  = ws + 86016;
    uint4* Pbf = (uint4*)ws;    // overwrites An (dead)

    k_norm<<<NN, 256, 0, stream>>>(adj, An, M1P);
    k_step<<<16, 256, 0, stream>>>(An, M1P, M2);   // M2 = aI + b*An*M1
    k_step<<<16, 256, 0, stream>>>(An, M2, M1P);   // P  = aI + b*An*M2
    k_pack<<<91, 64, 0, stream>>>(M1P, Pbf);
    k_main<<<256, 512, 0, stream>>>(x, Pbf, W, b, out);
}

// Round 4
// 223.759 us; speedup vs baseline: 1.9571x; 1.1682x over previous
//
#include <hip/hip_runtime.h>

#define NN 207
#define ALPHA 0.05f
#define BETA  0.95f

typedef __attribute__((ext_vector_type(8))) short bf16x8;
typedef __attribute__((ext_vector_type(4))) float f32x4;

__device__ inline unsigned short f2bf(float f) {
    union { float f; unsigned int u; } v; v.f = f;
    unsigned int u = v.u;
    return (unsigned short)((u + 0x7FFFu + ((u >> 16) & 1u)) >> 16);   // RNE
}

// ---- adjacency normalize: An = (adj+I)/rowsum, M1 = alpha*I + beta*An
__global__ __launch_bounds__(256) void k_norm(const float* __restrict__ adj,
                                              float* __restrict__ An,
                                              float* __restrict__ M1) {
    int v = blockIdx.x;
    int t = threadIdx.x;
    __shared__ float red[4];
    __shared__ float sinv;
    float s = 0.f;
    if (t < NN) s = adj[v * NN + t];
    s += __shfl_down(s, 32); s += __shfl_down(s, 16); s += __shfl_down(s, 8);
    s += __shfl_down(s, 4);  s += __shfl_down(s, 2);  s += __shfl_down(s, 1);
    if ((t & 63) == 0) red[t >> 6] = s;
    __syncthreads();
    if (t == 0) sinv = 1.0f / (red[0] + red[1] + red[2] + red[3] + 1.0f);
    __syncthreads();
    if (t < NN) {
        float val = (adj[v * NN + t] + (t == v ? 1.f : 0.f)) * sinv;
        An[v * NN + t] = val;
        M1[v * NN + t] = (t == v ? ALPHA : 0.f) + BETA * val;
    }
}

// ---- C = alpha*I + beta*(A @ X); 16x16 tile per block, 169 blocks
__global__ __launch_bounds__(256) void k_stepM(const float* __restrict__ A,
                                               const float* __restrict__ X,
                                               float* __restrict__ C) {
    __shared__ float As[16 * 208];
    __shared__ float Xs[16 * 212];
    const int t = threadIdx.x;
    const int i0 = (blockIdx.x / 13) * 16, j0 = (blockIdx.x % 13) * 16;
    const int r = t >> 4, cj = t & 15;
    for (int p = 0; p < 13; ++p) {
        int u = p * 16 + cj;
        As[r * 208 + u] = (i0 + r < NN && u < NN) ? A[(i0 + r) * NN + u] : 0.f;
        int u2 = p * 16 + r;
        Xs[cj * 212 + u2] = (u2 < NN && j0 + cj < NN) ? X[u2 * NN + j0 + cj] : 0.f;
    }
    __syncthreads();
    float s = 0.f;
    for (int u = 0; u < 208; u += 4) {
        float4 av = *(const float4*)&As[r * 208 + u];
        float4 xv = *(const float4*)&Xs[cj * 212 + u];
        s = fmaf(av.x, xv.x, s); s = fmaf(av.y, xv.y, s);
        s = fmaf(av.z, xv.z, s); s = fmaf(av.w, xv.w, s);
    }
    int gi = i0 + r, gj = j0 + cj;
    if (gi < NN && gj < NN)
        C[gi * NN + gj] = (gi == gj ? ALPHA : 0.f) + BETA * s;
}

// ---- P-tile = alpha*I + beta*(A @ X), packed straight to B-fragment order:
// Pbf[(nt*7+ks)*64 + (vv + 16*kblk)] = uint4 of 8 bf16, k = ks*32+kblk*8+j
__global__ __launch_bounds__(256) void k_stepP(const float* __restrict__ A,
                                               const float* __restrict__ X,
                                               uint4* __restrict__ Pbf) {
    __shared__ float As[16 * 208];
    __shared__ float Xs[16 * 212];
    __shared__ float Ct[16 * 17];
    const int t = threadIdx.x;
    const int nt = blockIdx.x / 13, jt = blockIdx.x % 13;
    const int i0 = nt * 16, j0 = jt * 16;
    const int r = t >> 4, cj = t & 15;
    for (int p = 0; p < 13; ++p) {
        int u = p * 16 + cj;
        As[r * 208 + u] = (i0 + r < NN && u < NN) ? A[(i0 + r) * NN + u] : 0.f;
        int u2 = p * 16 + r;
        Xs[cj * 212 + u2] = (u2 < NN && j0 + cj < NN) ? X[u2 * NN + j0 + cj] : 0.f;
    }
    __syncthreads();
    float s = 0.f;
    for (int u = 0; u < 208; u += 4) {
        float4 av = *(const float4*)&As[r * 208 + u];
        float4 xv = *(const float4*)&Xs[cj * 212 + u];
        s = fmaf(av.x, xv.x, s); s = fmaf(av.y, xv.y, s);
        s = fmaf(av.z, xv.z, s); s = fmaf(av.w, xv.w, s);
    }
    int gi = i0 + r, gj = j0 + cj;
    Ct[r * 17 + cj] = ((gi == gj && gi < NN) ? ALPHA : 0.f) + BETA * s;
    __syncthreads();
    if (t < 32) {
        const int vv = t & 15, kb2 = t >> 4;
        const int ks = jt >> 1;
        const int kblk = (jt & 1) * 2 + kb2;
        unsigned int d[4];
        #pragma unroll
        for (int p = 0; p < 4; ++p) {
            float lo = Ct[vv * 17 + kb2 * 8 + 2 * p];
            float hi = Ct[vv * 17 + kb2 * 8 + 2 * p + 1];
            d[p] = (unsigned int)f2bf(lo) | ((unsigned int)f2bf(hi) << 16);
        }
        uint4 o; o.x = d[0]; o.y = d[1]; o.z = d[2]; o.w = d[3];
        Pbf[(nt * 7 + ks) * 64 + vv + 16 * kblk] = o;
        if (jt == 12) {   // zero-fill ks=6, kblk 2..3 (w 208..223 pad)
            uint4 z; z.x = z.y = z.z = z.w = 0u;
            Pbf[(nt * 7 + 6) * 64 + vv + 16 * (2 + kb2)] = z;
        }
    }
}

// ---- main: block=(n,lseg); wave=Mtile; A-frags direct from global; no k-loop barriers
__global__ __launch_bounds__(512, 4) void k_main(const float* __restrict__ x,
                                                 const uint4* __restrict__ Pbf,
                                                 const float* __restrict__ Wm,
                                                 const float* __restrict__ bias,
                                                 float* __restrict__ out) {
    __shared__ float ys[128 * 33];   // 16.9 KB, epilogue only

    const int b = blockIdx.x;
    const int xcd = b & 7;
    const int q = b >> 3;
    const int lseg = q % 3;
    const int n = (q / 3) * 8 + xcd;   // 3 lseg-siblings of n share an XCD L2
    const int l0 = lseg * 4;

    const int t = threadIdx.x;
    const int lane = t & 63;
    const int wave = __builtin_amdgcn_readfirstlane(t >> 6);   // = Mtile 0..7

    // A fragment source: m = wave*16 + (lane&15); c = m>>2, dl = m&3; k-chunk = (lane>>4)*8
    const int c    = wave * 4 + ((lane >> 2) & 3);
    const int dl   = lane & 3;
    const int kblk = lane >> 4;
    const float* xp = x + ((size_t)(n * 32 + c) * NN + kblk * 8) * 12 + l0 + dl;

    f32x4 acc[13];
    #pragma unroll
    for (int i = 0; i < 13; ++i) acc[i] = (f32x4)0.f;

    for (int ks = 0; ks < 7; ++ks) {
        const float* xk = xp + ks * (32 * 12);
        float xv[8];
        if (ks < 6) {
            #pragma unroll
            for (int j = 0; j < 8; ++j) xv[j] = xk[j * 12];
        } else {
            #pragma unroll
            for (int j = 0; j < 8; ++j) {
                int w = 192 + kblk * 8 + j;
                xv[j] = (w < NN) ? xk[j * 12] : 0.f;
            }
        }
        uint4 araw;
        araw.x = (unsigned int)f2bf(xv[0]) | ((unsigned int)f2bf(xv[1]) << 16);
        araw.y = (unsigned int)f2bf(xv[2]) | ((unsigned int)f2bf(xv[3]) << 16);
        araw.z = (unsigned int)f2bf(xv[4]) | ((unsigned int)f2bf(xv[5]) << 16);
        araw.w = (unsigned int)f2bf(xv[6]) | ((unsigned int)f2bf(xv[7]) << 16);
        bf16x8 af = __builtin_bit_cast(bf16x8, araw);

        const uint4* pb = Pbf + ks * 64 + lane;
        #pragma unroll
        for (int nt = 0; nt < 13; ++nt) {
            bf16x8 bfr = __builtin_bit_cast(bf16x8, pb[nt * 448]);
            acc[nt] = __builtin_amdgcn_mfma_f32_16x16x32_bf16(af, bfr, acc[nt], 0, 0, 0);
        }
    }

    // ---- epilogue: fp32 channel mix; ys[slot = ntl*64 + vloc*4 + dl][c], str 33
    const int s   = t & 127;
    const int og  = __builtin_amdgcn_readfirstlane(t >> 7);
    const int vloc = (s >> 2) & 15;
    const int dlo  = s & 3;
    const int ntl  = s >> 6;

    #pragma unroll
    for (int np = 0; np < 7; ++np) {
        __syncthreads();
        #pragma unroll
        for (int ntw = 0; ntw < 2; ++ntw) {
            int nt = np * 2 + ntw;
            if (nt < 13) {
                #pragma unroll
                for (int r = 0; r < 4; ++r)
                    ys[(ntw * 64 + (lane & 15) * 4 + r) * 33 + wave * 4 + (lane >> 4)] = acc[nt][r];
            }
        }
        __syncthreads();
        int nt = np * 2 + ntl;
        int v = nt * 16 + vloc;
        if (nt < 13 && v < NN) {
            float y[32];
            #pragma unroll
            for (int cc = 0; cc < 32; ++cc) y[cc] = ys[s * 33 + cc];
            size_t ob = ((size_t)(n * 32) * NN + v) * 12 + l0 + dlo;
            #pragma unroll
            for (int oo = 0; oo < 8; ++oo) {
                int o = og * 8 + oo;
                float a = bias[o];
                #pragma unroll
                for (int cc = 0; cc < 32; ++cc)
                    a = fmaf(Wm[o * 32 + cc], y[cc], a);
                out[ob + (size_t)o * (NN * 12)] = a;
            }
        }
    }
}

extern "C" void kernel_launch(void* const* d_in, const int* in_sizes, int n_in,
                              void* d_out, int out_size, void* d_ws, size_t ws_size,
                              hipStream_t stream) {
    const float* x   = (const float*)d_in[0];
    const float* adj = (const float*)d_in[1];
    const float* W   = (const float*)d_in[2];
    const float* b   = (const float*)d_in[3];
    float* out = (float*)d_out;
    float* ws  = (float*)d_ws;

    float* An  = ws;                      // 207*207
    float* M1  = ws + 43008;
    float* M2  = ws + 86016;
    uint4* Pbf = (uint4*)(ws + 129024);   // 13*7*64 uint4 = 93 KB

    k_norm <<<NN, 256, 0, stream>>>(adj, An, M1);
    k_stepM<<<169, 256, 0, stream>>>(An, M1, M2);    // M2 = aI + b*An*M1
    k_stepP<<<169, 256, 0, stream>>>(An, M2, Pbf);   // P packed to B-frags
    k_main <<<768, 512, 0, stream>>>(x, Pbf, W, b, out);
}